// Round 3
// baseline (96.162 us; speedup 1.0000x reference)
//
#include <hip/hip_runtime.h>
#include <math.h>

#define B_TOTAL 2048
#define I_TOTAL 2048
#define O_TOTAL 2048
#define KW 64
#define NIN 6
#define BLOCK 256
#define T_O 16                     // o's per main block
#define TPOSE_BLOCKS 1024          // (2048/64)^2
#define WPREP_BLOCKS 512           // 2048*64/256
#define MAIN_BLOCKS ((B_TOTAL / BLOCK) * (O_TOTAL / T_O))   /* 8*128 = 1024 */

// ---------------------------------------------------------------------------
// prep_all: one launch doing three independent jobs, selected by blockIdx.
//  blocks [0,1024):    xT[i][b] = x[b][i]   (64x64 LDS tile transpose)
//  blocks [1024,1536): wP[o][k] row-major:  k<32: sigmoid(table[o][k])
//                      k>=32:   sigmoid(table[o][k]) - sigmoid(table[o][k-32])
//                      + mapping -> int32 m32[o][6] (int64/int32 auto-detect)
// ---------------------------------------------------------------------------
__global__ __launch_bounds__(BLOCK) void prep_all(
    const float* __restrict__ x,
    const float* __restrict__ table,
    const unsigned int* __restrict__ map_raw,
    float* __restrict__ xT,
    float* __restrict__ wP,
    int*   __restrict__ m32)
{
    const int bid = blockIdx.x, tid = threadIdx.x;

    if (bid < TPOSE_BLOCKS) {
        __shared__ float sm[64][65];              // +1 pad: conflict-free cols
        const int bi = bid >> 5, bj = bid & 31;   // 32x32 grid of 64x64 tiles
        const int col = tid & 63, w = tid >> 6;
        #pragma unroll
        for (int r8 = 0; r8 < 16; ++r8) {
            int row = r8 * 4 + w;
            sm[row][col] = x[(size_t)(bi * 64 + row) * I_TOTAL + bj * 64 + col];
        }
        __syncthreads();
        #pragma unroll
        for (int r8 = 0; r8 < 16; ++r8) {
            int row = r8 * 4 + w;
            // xT[bj*64+row][bi*64+col] = x[bi*64+col][bj*64+row]
            xT[(size_t)(bj * 64 + row) * B_TOTAL + bi * 64 + col] = sm[col][row];
        }
    } else {
        const int gid = (bid - TPOSE_BLOCKS) * BLOCK + tid;   // 0..131071
        float v = table[gid];
        float s = 1.0f / (1.0f + __expf(-v));
        if ((gid & 63) >= 32) {
            float v0 = table[gid - 32];
            s -= 1.0f / (1.0f + __expf(-v0));
        }
        wP[gid] = s;

        if (gid < O_TOTAL * NIN) {
            // int64 little-endian with values < 2048 => odd u32 words all 0.
            bool is64 = ((map_raw[1] | map_raw[3] | map_raw[5] | map_raw[7]) == 0u);
            m32[gid] = is64 ? (int)map_raw[2 * gid] : (int)map_raw[gid];
        }
    }
}

// ---------------------------------------------------------------------------
// Main, v3: lanes over b (not o).
//  * the 6 x-gathers become COALESCED uniform-row loads xT[m[i]][b0+lane]
//    (was: 6 random LDS gathers per output = the LDS-pipe bottleneck)
//  * weights/mapping are wave-uniform -> scalar (s_load) broadcasts
//  * out staged via padded LDS tile so global writes stay coalesced
//  * bx = bid&7: with round-robin dispatch each XCD keeps its 2MB xT
//    column-slice + 2MB out row-slice L2-resident (perf-only assumption)
//  * #pragma unroll 2 on the o-loop: overlap o+1's 6 L2 loads with o's
//    63-FMA dependent chain
// ---------------------------------------------------------------------------
__global__ __launch_bounds__(BLOCK, 2) void lut_main(
    const float* __restrict__ xT,
    const float* __restrict__ wP,
    const int*   __restrict__ m32,
    float*       __restrict__ out)
{
    __shared__ float os[T_O][BLOCK + 2];   // +2 pad: conflict-free write phase

    const int tid = threadIdx.x, bid = blockIdx.x;
    const int bx = bid & 7;                // batch-block  (XCD affinity)
    const int oy = bid >> 3;               // o-tile index
    const int o0 = oy * T_O;
    const float* xb = xT + (size_t)bx * BLOCK + tid;   // this lane's b column

    #pragma unroll 2
    for (int ol = 0; ol < T_O; ++ol) {
        const int o = o0 + ol;

        const int* mp = m32 + o * NIN;     // uniform -> scalar loads
        float xv[NIN];
        #pragma unroll
        for (int i = 0; i < NIN; ++i)
            xv[i] = xb[(size_t)mp[i] * B_TOTAL];       // coalesced 1KB loads

        const float4* wp = (const float4*)(wP + (size_t)o * KW);  // uniform
        float4 wa[16];
        #pragma unroll
        for (int j = 0; j < 16; ++j) wa[j] = wp[j];

        // multilinear contraction; level 0 uses precomputed lo/diff
        float tt[32];
        #pragma unroll
        for (int j = 0; j < 8; ++j) {
            tt[4 * j + 0] = fmaf(xv[5], wa[j + 8].x, wa[j].x);
            tt[4 * j + 1] = fmaf(xv[5], wa[j + 8].y, wa[j].y);
            tt[4 * j + 2] = fmaf(xv[5], wa[j + 8].z, wa[j].z);
            tt[4 * j + 3] = fmaf(xv[5], wa[j + 8].w, wa[j].w);
        }
        #pragma unroll
        for (int j = 0; j < 16; ++j) tt[j] = fmaf(xv[4], tt[j + 16] - tt[j], tt[j]);
        #pragma unroll
        for (int j = 0; j < 8;  ++j) tt[j] = fmaf(xv[3], tt[j + 8]  - tt[j], tt[j]);
        #pragma unroll
        for (int j = 0; j < 4;  ++j) tt[j] = fmaf(xv[2], tt[j + 4]  - tt[j], tt[j]);
        #pragma unroll
        for (int j = 0; j < 2;  ++j) tt[j] = fmaf(xv[1], tt[j + 2]  - tt[j], tt[j]);
        float res = fmaf(xv[0], tt[1] - tt[0], tt[0]);

        os[ol][tid] = res;                 // banks (2*ol+tid)%32: conflict-free
    }

    __syncthreads();

    // coalesced out write: out[b0+r][o0 .. o0+15] from LDS columns
    #pragma unroll
    for (int rep = 0; rep < T_O; ++rep) {
        int idx = rep * BLOCK + tid;
        int o_l = idx & (T_O - 1);
        int r   = idx / T_O;
        out[(size_t)(bx * BLOCK + r) * O_TOTAL + o0 + o_l] = os[o_l][r];
    }
}

extern "C" void kernel_launch(void* const* d_in, const int* in_sizes, int n_in,
                              void* d_out, int out_size, void* d_ws, size_t ws_size,
                              hipStream_t stream)
{
    const float*        x       = (const float*)d_in[0];
    const float*        table   = (const float*)d_in[1];
    const unsigned int* map_raw = (const unsigned int*)d_in[2];
    float* out = (float*)d_out;

    // workspace layout
    float* xT  = (float*)d_ws;                                   // 16 MiB
    float* wP  = (float*)((char*)d_ws + (size_t)16 * 1024 * 1024);   // 512 KiB
    int*   m32 = (int*)  ((char*)d_ws + (size_t)16 * 1024 * 1024 + 512 * 1024); // 48 KiB

    prep_all<<<TPOSE_BLOCKS + WPREP_BLOCKS, BLOCK, 0, stream>>>(
        x, table, map_raw, xT, wP, m32);

    lut_main<<<MAIN_BLOCKS, BLOCK, 0, stream>>>(xT, wP, m32, out);
}

// Round 4
// 86.864 us; speedup vs baseline: 1.1070x; 1.1070x over previous
//
#include <hip/hip_runtime.h>
#include <math.h>

#define B_TOTAL 2048
#define I_TOTAL 2048
#define O_TOTAL 2048
#define KW 64
#define NIN 6
#define BLOCK 256
#define TILE_B 8                    // b-rows staged per block (64 KB LDS)
#define T_O 1024                    // o's swept per block (half of O)
#define OC_N (T_O / BLOCK)          // 4 o-chunks per block
#define MAIN_BLOCKS ((B_TOTAL / TILE_B) * (O_TOTAL / T_O))   /* 256*2 = 512 */

// ---------------------------------------------------------------------------
// prep_kernel (verbatim from the Round-1 PASSED version):
//  blocks 0..31: table -> wT[k][o] via 64x65 LDS transpose (coalesced writes)
//     k<32 : sigmoid(table[o][k])                         ("lo")
//     k>=32: sigmoid(table[o][k]) - sigmoid(table[o][k-32]) (diff)
//  all 48 blocks: mapping -> transposed int32 m32T[i][o]
// ---------------------------------------------------------------------------
__global__ __launch_bounds__(BLOCK) void prep_kernel(
    const float* __restrict__ table,
    const unsigned int* __restrict__ map_raw,
    float* __restrict__ wT,
    int* __restrict__ m32T)
{
    const int t = threadIdx.x;

    if (blockIdx.x < 32) {
        __shared__ float sm[64][65];          // +1 pad: conflict-free col reads
        const int o0 = blockIdx.x * 64;
        #pragma unroll
        for (int rep = 0; rep < 16; ++rep) {
            int idx = rep * 256 + t;          // 0..4095
            int ol = idx >> 6, k = idx & 63;
            float v = table[(o0 + ol) * KW + k];      // coalesced read
            sm[ol][k] = 1.0f / (1.0f + __expf(-v));
        }
        __syncthreads();
        #pragma unroll
        for (int rep = 0; rep < 16; ++rep) {
            int idx = rep * 256 + t;
            int k = idx >> 6, ol = idx & 63;
            float s = sm[ol][k];
            float v = (k >= 32) ? (s - sm[ol][k - 32]) : s;
            wT[k * O_TOTAL + o0 + ol] = v;            // coalesced write
        }
    }

    const int gid = blockIdx.x * BLOCK + t;           // 48*256 = 12288 exactly
    if (gid < O_TOTAL * NIN) {
        // int64 little-endian with values < 2048 => odd u32 words are all 0.
        bool is64 = ((map_raw[1] | map_raw[3] | map_raw[5] | map_raw[7]) == 0u);
        int val = is64 ? (int)map_raw[2 * gid] : (int)map_raw[gid];
        int oo = gid / NIN, ii = gid - oo * NIN;
        m32T[ii * O_TOTAL + oo] = val;
    }
}

// ---------------------------------------------------------------------------
// Main, v4 — maximize reuse per staged byte (traffic theory):
//  * each block stages TILE_B=8 x-rows ONCE (64 KB LDS, async global_load_lds)
//    and sweeps T_O=1024 o's over them -> x HBM traffic 32 MB (was 128 MB),
//    wT stays L2-resident (512 KB total), out written once.
//  * ONE __syncthreads total; compute phase is barrier-free.
//  * block pairing: btile = bid&255, ohalf = bid>>8  => the two blocks
//    sharing a b-tile differ by 256 == 0 (mod 8) -> same XCD -> the 2nd
//    x-tile read is an L2 hit (perf-only assumption).
//  * lanes = o: weights/mapping loads coalesced (wT[k][o], m32T[i][o]);
//    x gathers are LDS random reads (~2x bank cost, the accepted floor).
// ---------------------------------------------------------------------------
__device__ __forceinline__ void async_cp16(float* lds, const float* g)
{
    __builtin_amdgcn_global_load_lds(
        (const __attribute__((address_space(1))) void*)g,
        (__attribute__((address_space(3))) void*)lds,
        16, 0, 0);
}

__global__ __launch_bounds__(BLOCK, 2) void lut_main(
    const float* __restrict__ x,
    const float* __restrict__ wT,
    const int*   __restrict__ m32T,
    float*       __restrict__ out)
{
    __shared__ float xs[TILE_B * I_TOTAL];   // 8 rows x 8 KB = 64 KB

    const int tid   = threadIdx.x;
    const int btile = blockIdx.x & 255;      // fast index: b-tile
    const int ohalf = blockIdx.x >> 8;       // slow index: o-half
    const int b0    = btile * TILE_B;
    const int obase = ohalf * T_O;

    // ---- stage 8 rows of x into LDS (async DMA, one barrier) -------------
    {
        const float* src = x + (size_t)b0 * I_TOTAL;
        #pragma unroll
        for (int it = 0; it < (TILE_B * I_TOTAL / 4) / BLOCK; ++it) {  // 16
            int f = it * BLOCK + tid;        // float4 index; wave-uniform base
            async_cp16(&xs[4 * f], src + 4 * f);
        }
    }
    __syncthreads();   // drains vmcnt(0) then barrier; last barrier in kernel

    // ---- sweep 1024 o's in 4 chunks of 256 -------------------------------
    for (int oc = 0; oc < OC_N; ++oc) {
        const int o = obase + oc * BLOCK + tid;

        int mm[NIN];
        #pragma unroll
        for (int i = 0; i < NIN; ++i) mm[i] = m32T[i * O_TOTAL + o];  // coalesced

        float ww[KW];
        #pragma unroll
        for (int k = 0; k < KW; ++k) ww[k] = wT[k * O_TOTAL + o];     // coalesced

        #pragma unroll
        for (int r = 0; r < TILE_B; ++r) {
            const float* xr = xs + r * I_TOTAL;
            float xv[NIN];
            #pragma unroll
            for (int i = 0; i < NIN; ++i) xv[i] = xr[mm[i]];   // LDS gather

            // multilinear contraction; level 0 uses precomputed lo/diff
            float tt[32];
            #pragma unroll
            for (int j = 0; j < 32; ++j) tt[j] = fmaf(xv[5], ww[j + 32], ww[j]);
            #pragma unroll
            for (int j = 0; j < 16; ++j) tt[j] = fmaf(xv[4], tt[j + 16] - tt[j], tt[j]);
            #pragma unroll
            for (int j = 0; j < 8;  ++j) tt[j] = fmaf(xv[3], tt[j + 8]  - tt[j], tt[j]);
            #pragma unroll
            for (int j = 0; j < 4;  ++j) tt[j] = fmaf(xv[2], tt[j + 4]  - tt[j], tt[j]);
            #pragma unroll
            for (int j = 0; j < 2;  ++j) tt[j] = fmaf(xv[1], tt[j + 2]  - tt[j], tt[j]);
            float res = fmaf(xv[0], tt[1] - tt[0], tt[0]);

            out[(size_t)(b0 + r) * O_TOTAL + o] = res;         // coalesced
        }
    }
}

extern "C" void kernel_launch(void* const* d_in, const int* in_sizes, int n_in,
                              void* d_out, int out_size, void* d_ws, size_t ws_size,
                              hipStream_t stream)
{
    const float*        x       = (const float*)d_in[0];
    const float*        table   = (const float*)d_in[1];
    const unsigned int* map_raw = (const unsigned int*)d_in[2];
    float* out  = (float*)d_out;
    float* wT   = (float*)d_ws;                                        // 512 KB
    int*   m32T = (int*)((char*)d_ws + (size_t)O_TOTAL * KW * sizeof(float)); // +48 KB

    prep_kernel<<<48, BLOCK, 0, stream>>>(table, map_raw, wT, m32T);

    lut_main<<<MAIN_BLOCKS, BLOCK, 0, stream>>>(x, wT, m32T, out);
}